// Round 9
// baseline (121.490 us; speedup 1.0000x reference)
//
#include <hip/hip_runtime.h>
#include <math.h>

// Canny-style Sobel NMS + double threshold on 4096x4096 f32.
// Reference's direction predicate b1 is vacuously true -> NMS is horizontal.
//
// R9: per-CU vector-memory data-path model (ceiling ~10.1 B/cyc/CU, from the
// 268MB fill @43us). R4 hit 92% of it at VGPR 28 / 8 waves per SIMD; R8 cut
// bytes 1.77x but fell to 70% (VGPR > 64 halved occupancy). This round keeps
// R8's 1.25x read amplification and packed-halo trick but shrinks state:
// ROWS=4 per lane, __launch_bounds__(256,8) pins VGPR <= 64 -> 8 waves/SIMD,
// 16K waves for deep MLP. 11 full-width mem insts per wave.
// Math identical to the verified absmax-0.0 path: exact squared-domain NMS +
// double threshold with integer hazard net -> rare sqrtf reference fallback.

constexpr int Wd = 4096;
constexpr int Ht = 4096;
constexpr int ROWS = 4;

typedef float f4 __attribute__((ext_vector_type(4)));
typedef float f2 __attribute__((ext_vector_type(2)));

__global__ __launch_bounds__(256, 8) void canny_kernel(const float* __restrict__ x,
                                                       float* __restrict__ out) {
    const int tid  = threadIdx.x;
    const int lane = tid & 63;
    const int wv   = tid >> 6;
    const int wc   = blockIdx.x;                     // 256-col band, 0..15
    const int cbase = wc * 256;
    const int c     = cbase + lane * 4;              // lane's first col
    const int r0    = (blockIdx.y * 4 + wv) * ROWS;  // wave's first output row

    // ---- Main loads: 6 coalesced f4 row-chunks (1KB/instruction) ----
    f4 X[ROWS + 2];
    #pragma unroll
    for (int k = 0; k < ROWS + 2; ++k) {
        int rr = r0 - 1 + k;
        rr = rr < 0 ? 0 : (rr > Ht - 1 ? Ht - 1 : rr);  // border rows zeroed below
        X[k] = *(const f4*)(x + (size_t)rr * Wd + c);
    }

    // ---- Halo: ONE masked load covers both sides x all 6 rows ----
    // lane k (k<6):  left halo f2 (cols cbase-2, cbase-1) of row r0-1+k
    // lane 32+k:     right halo f2 (cols cbase+256, +257) of row r0-1+k
    // Image-edge bands load nothing -> zeros (matches the zero-pad conv).
    f2 hl = {0.f, 0.f};
    {
        const int  hk    = lane & 31;
        const bool left  = lane < 32;
        const bool valid = (hk < ROWS + 2) && (left ? (wc > 0) : (wc < 15));
        if (valid) {
            int rr = r0 - 1 + hk;
            rr = rr < 0 ? 0 : (rr > Ht - 1 ? Ht - 1 : rr);
            const int hc = left ? cbase - 2 : cbase + 256;
            hl = *(const f2*)(x + (size_t)rr * Wd + hc);
        }
    }
    // Per-lane halo t: lane (side*32 + o) holds the t-halo for output row r0+o.
    const float s1x = __shfl_down(hl.x, 1), s2x = __shfl_down(hl.x, 2);
    const float s1y = __shfl_down(hl.y, 1), s2y = __shfl_down(hl.y, 2);
    const float th1x = hl.x + 2.0f * s1x + s2x;   // t1 of halo col 0
    const float th1y = hl.y + 2.0f * s1y + s2y;   // t1 of halo col 1
    const float th2x = hl.x - s2x;                // t2 of halo col 0
    const float th2y = hl.y - s2y;                // t2 of halo col 1

    const float C1  = __uint_as_float(0x3CB851EDu);  // q > C1  <=> sqrt(q) > 0.15f
    const float C2B = __uint_as_float(0x3B23D709u);  // q > C2B <=> sqrt(q) >= 0.05f

    #pragma unroll
    for (int o = 0; o < ROWS; ++o) {
        const int r = r0 + o;
        f4 a = X[o], b = X[o + 1], cc = X[o + 2];

        // Vertical pass for own 4 cols: t1 = a+2b+c (gx), t2 = a-c (gy).
        float t1[4], t2[4];
        #pragma unroll
        for (int j = 0; j < 4; ++j) {
            t1[j] = a[j] + 2.0f * b[j] + cc[j];
            t2[j] = a[j] - cc[j];
        }

        // Halo broadcast: lane 0 wants left (lane o), lane 63 right (lane 32+o).
        const int hidx = (lane == 63) ? 32 + o : o;
        const float b1x = __shfl(th1x, hidx);
        const float b1y = __shfl(th1y, hidx);
        const float b2x = __shfl(th2x, hidx);
        const float b2y = __shfl(th2y, hidx);

        // Neighbor t via shuffle: left lane's cols 2,3 / right lane's cols 0,1.
        float l1a = __shfl_up(t1[2], 1),   l1b = __shfl_up(t1[3], 1);
        float l2a = __shfl_up(t2[2], 1),   l2b = __shfl_up(t2[3], 1);
        float r1a = __shfl_down(t1[0], 1), r1b = __shfl_down(t1[1], 1);
        float r2a = __shfl_down(t2[0], 1), r2b = __shfl_down(t2[1], 1);
        if (lane == 0)  { l1a = b1x; l1b = b1y; l2a = b2x; l2b = b2y; }
        if (lane == 63) { r1a = b1x; r1b = b1y; r2a = b2x; r2b = b2y; }

        // T index k = image col c + (k-2), k = 0..7.
        float T1[8] = {l1a, l1b, t1[0], t1[1], t1[2], t1[3], r1a, r1b};
        float T2[8] = {l2a, l2b, t2[0], t2[1], t2[2], t2[3], r2a, r2b};

        // Squared gradient magnitude q[i] at image col c + (i-1), i = 0..5.
        float q[6];
        #pragma unroll
        for (int i = 0; i < 6; ++i) {
            float gx = T1[i + 2] - T1[i];
            float gy = T2[i] + 2.0f * T2[i + 1] + T2[i + 2];
            q[i] = gx * gx + gy * gy;
        }

        // Hazard net: near-tie q pairs could flip >= after sqrt rounding.
        bool hazard = false;
        #pragma unroll
        for (int i = 0; i < 5; ++i) {
            int d = (int)(__float_as_uint(q[i + 1]) - __float_as_uint(q[i]));
            hazard |= ((unsigned)(d + 8) < 17u);
        }

        float acc[4];
        #pragma unroll
        for (int o2 = 0; o2 < 4; ++o2) {
            float qp = q[o2], qc = q[o2 + 1], qn = q[o2 + 2];
            bool keep = (qc >= qp) && (qc >= qn);
            acc[o2] = (keep && qc > C1) ? 255.0f : 0.0f;
            hazard |= (keep && qc > 0.0f && qc <= C2B);  // pass-through needs sqrt
        }

        if (__any(hazard)) {
            // Exact reference path (rare).
            float m[6];
            #pragma unroll
            for (int i = 0; i < 6; ++i) m[i] = sqrtf(q[i]);
            #pragma unroll
            for (int o2 = 0; o2 < 4; ++o2) {
                float mc = m[o2 + 1];
                bool keep = (mc >= m[o2]) && (mc >= m[o2 + 2]);
                float e = keep ? mc : 0.0f;
                acc[o2] = (e > 0.15f) ? 255.0f : ((e >= 0.05f) ? 0.0f : e);
            }
        }

        // Zero border shell, exactly as the reference.
        if (r == 0 || r == Ht - 1) {
            #pragma unroll
            for (int o2 = 0; o2 < 4; ++o2) acc[o2] = 0.0f;
        }
        if (wc == 0  && lane == 0)  acc[0] = 0.0f;
        if (wc == 15 && lane == 63) acc[3] = 0.0f;

        f4 v = {acc[0], acc[1], acc[2], acc[3]};
        __builtin_nontemporal_store(v, (f4*)(out + (size_t)r * Wd + c));
    }
}

extern "C" void kernel_launch(void* const* d_in, const int* in_sizes, int n_in,
                              void* d_out, int out_size, void* d_ws, size_t ws_size,
                              hipStream_t stream) {
    const float* x = (const float*)d_in[0];
    float* out = (float*)d_out;
    dim3 grid(16, 256);   // 16 col-bands x 256 blocks of (4 waves x 4 rows)
    canny_kernel<<<grid, dim3(256), 0, stream>>>(x, out);
}

// Round 10
// 114.379 us; speedup vs baseline: 1.0622x; 1.0622x over previous
//
#include <hip/hip_runtime.h>
#include <math.h>

// Canny-style Sobel NMS + double threshold on 4096x4096 f32.
// Reference's direction predicate b1 is vacuously true -> NMS is horizontal.
//
// R10: R8's byte structure (1.25x read amp, packed one-instruction halo,
// 19 full-width mem insts/wave) + full occupancy. R8 held X[10] f4 upfront
// (~100 VGPR -> 4 waves/SIMD, occupancy cliff at 64). Here the row window is
// a rolling 5-register pipeline (prefetch distance 2) inside a non-unrolled
// loop, so live state ~55 VGPR -> fits __launch_bounds__(256,8) = 8 waves/
// SIMD without spilling (R9's regression = spills from a fully-unrolled body
// under the same cap). 8192 waves = exactly 2 residency sets.
// Math identical to the verified absmax-0.0 path: exact squared-domain NMS +
// double threshold with integer hazard net -> rare sqrtf reference fallback.

constexpr int Wd = 4096;
constexpr int Ht = 4096;
constexpr int ROWS = 8;

typedef float f4 __attribute__((ext_vector_type(4)));
typedef float f2 __attribute__((ext_vector_type(2)));

__global__ __launch_bounds__(256, 8) void canny_kernel(const float* __restrict__ x,
                                                       float* __restrict__ out) {
    const int tid  = threadIdx.x;
    const int lane = tid & 63;
    const int wv   = tid >> 6;
    const int wc   = blockIdx.x;                     // 256-col band, 0..15
    const int cbase = wc * 256;
    const int c     = cbase + lane * 4;              // lane's first col
    const int r0    = (blockIdx.y * 4 + wv) * ROWS;  // wave's first output row

    // ---- Halo: ONE masked load covers both sides x all 10 window rows ----
    // lane k (k<10): left halo f2 (cols cbase-2,-1) of row r0-1+k
    // lane 32+k:     right halo f2 (cols cbase+256,+257) of row r0-1+k
    f2 hl = {0.f, 0.f};
    {
        const int  hk    = lane & 31;
        const bool left  = lane < 32;
        const bool valid = (hk < ROWS + 2) && (left ? (wc > 0) : (wc < 15));
        if (valid) {
            int rr = r0 - 1 + hk;
            rr = rr < 0 ? 0 : (rr > Ht - 1 ? Ht - 1 : rr);
            const int hc = left ? cbase - 2 : cbase + 256;
            hl = *(const f2*)(x + (size_t)rr * Wd + hc);
        }
    }
    // Per-lane halo t: lane (side*32 + o) holds the t-halo for output row r0+o.
    const float s1x = __shfl_down(hl.x, 1), s2x = __shfl_down(hl.x, 2);
    const float s1y = __shfl_down(hl.y, 1), s2y = __shfl_down(hl.y, 2);
    const float th1x = hl.x + 2.0f * s1x + s2x;   // t1 of halo col 0
    const float th1y = hl.y + 2.0f * s1y + s2y;   // t1 of halo col 1
    const float th2x = hl.x - s2x;                // t2 of halo col 0
    const float th2y = hl.y - s2y;                // t2 of halo col 1

    // Rolling-window row loads: k = 0..9 -> input row r0-1+k (clamped; the
    // clamped rows only feed outputs that are force-zeroed below).
    auto ld = [&](int k) -> f4 {
        int rr = r0 - 1 + k;
        rr = rr < 0 ? 0 : (rr > Ht - 1 ? Ht - 1 : rr);
        return *(const f4*)(x + (size_t)rr * Wd + c);
    };

    f4 xa = ld(0), xb = ld(1), xc = ld(2), xd = ld(3);   // 4 loads in flight

    const float C1  = __uint_as_float(0x3CB851EDu);  // q > C1  <=> sqrt(q) > 0.15f
    const float C2B = __uint_as_float(0x3B23D709u);  // q > C2B <=> sqrt(q) >= 0.05f

    float* op = out + (size_t)r0 * Wd + c;

    #pragma unroll 1
    for (int o = 0; o < ROWS; ++o) {
        // Prefetch (distance 2): row k = o+4, consumed at iteration o+2.
        f4 xe = (o < ROWS - 2) ? ld(o + 4) : xd;

        // Vertical pass for own 4 cols: t1 = a+2b+c (gx), t2 = a-c (gy).
        float t1[4], t2[4];
        #pragma unroll
        for (int j = 0; j < 4; ++j) {
            t1[j] = xa[j] + 2.0f * xb[j] + xc[j];
            t2[j] = xa[j] - xc[j];
        }

        // Halo broadcast: lane 0 wants left (lane o), lane 63 right (lane 32+o).
        const int hidx = (lane == 63) ? 32 + o : o;
        const float b1x = __shfl(th1x, hidx);
        const float b1y = __shfl(th1y, hidx);
        const float b2x = __shfl(th2x, hidx);
        const float b2y = __shfl(th2y, hidx);

        // Neighbor t via shuffle: left lane's cols 2,3 / right lane's cols 0,1.
        float l1a = __shfl_up(t1[2], 1),   l1b = __shfl_up(t1[3], 1);
        float l2a = __shfl_up(t2[2], 1),   l2b = __shfl_up(t2[3], 1);
        float r1a = __shfl_down(t1[0], 1), r1b = __shfl_down(t1[1], 1);
        float r2a = __shfl_down(t2[0], 1), r2b = __shfl_down(t2[1], 1);
        if (lane == 0)  { l1a = b1x; l1b = b1y; l2a = b2x; l2b = b2y; }
        if (lane == 63) { r1a = b1x; r1b = b1y; r2a = b2x; r2b = b2y; }

        // T index k = image col c + (k-2), k = 0..7.
        float T1[8] = {l1a, l1b, t1[0], t1[1], t1[2], t1[3], r1a, r1b};
        float T2[8] = {l2a, l2b, t2[0], t2[1], t2[2], t2[3], r2a, r2b};

        // Squared gradient magnitude q[i] at image col c + (i-1), i = 0..5.
        float q[6];
        #pragma unroll
        for (int i = 0; i < 6; ++i) {
            float gx = T1[i + 2] - T1[i];
            float gy = T2[i] + 2.0f * T2[i + 1] + T2[i + 2];
            q[i] = gx * gx + gy * gy;
        }

        // Hazard net: near-tie q pairs could flip >= after sqrt rounding.
        bool hazard = false;
        #pragma unroll
        for (int i = 0; i < 5; ++i) {
            int d = (int)(__float_as_uint(q[i + 1]) - __float_as_uint(q[i]));
            hazard |= ((unsigned)(d + 8) < 17u);
        }

        float acc[4];
        #pragma unroll
        for (int o2 = 0; o2 < 4; ++o2) {
            float qp = q[o2], qc = q[o2 + 1], qn = q[o2 + 2];
            bool keep = (qc >= qp) && (qc >= qn);
            acc[o2] = (keep && qc > C1) ? 255.0f : 0.0f;
            hazard |= (keep && qc > 0.0f && qc <= C2B);  // pass-through needs sqrt
        }

        if (__any(hazard)) {
            // Exact reference path (rare).
            float m[6];
            #pragma unroll
            for (int i = 0; i < 6; ++i) m[i] = sqrtf(q[i]);
            #pragma unroll
            for (int o2 = 0; o2 < 4; ++o2) {
                float mc = m[o2 + 1];
                bool keep = (mc >= m[o2]) && (mc >= m[o2 + 2]);
                float e = keep ? mc : 0.0f;
                acc[o2] = (e > 0.15f) ? 255.0f : ((e >= 0.05f) ? 0.0f : e);
            }
        }

        // Zero border shell, exactly as the reference.
        const int r = r0 + o;
        if (r == 0 || r == Ht - 1) {
            #pragma unroll
            for (int o2 = 0; o2 < 4; ++o2) acc[o2] = 0.0f;
        }
        if (wc == 0  && lane == 0)  acc[0] = 0.0f;
        if (wc == 15 && lane == 63) acc[3] = 0.0f;

        f4 v = {acc[0], acc[1], acc[2], acc[3]};
        __builtin_nontemporal_store(v, (f4*)op);
        op += Wd;

        // Rotate the window.
        xa = xb; xb = xc; xc = xd; xd = xe;
    }
}

extern "C" void kernel_launch(void* const* d_in, const int* in_sizes, int n_in,
                              void* d_out, int out_size, void* d_ws, size_t ws_size,
                              hipStream_t stream) {
    const float* x = (const float*)d_in[0];
    float* out = (float*)d_out;
    dim3 grid(16, 128);   // 16 col-bands x 128 blocks of (4 waves x 8 rows)
    canny_kernel<<<grid, dim3(256), 0, stream>>>(x, out);
}

// Round 11
// 113.281 us; speedup vs baseline: 1.0725x; 1.0097x over previous
//
#include <hip/hip_runtime.h>
#include <math.h>

// Canny-style Sobel NMS + double threshold on 4096x4096 f32.
// Reference's direction predicate b1 is vacuously true -> NMS is horizontal.
//
// R11: R8's winning structure (all loads issued up front, packed one-
// instruction halo, shfl horizontal sharing, exact squared-domain NMS with
// hazard-netted sqrtf fallback) extended to ROWS=16: 18 row loads + 1 halo
// load in flight per wave (R8: 11), read amp 1.125x (R8: 1.25x), 2.19 mem
// insts/row (R8: 2.375). Evidence (R8 vs R9/R10): per-wave loads-in-flight,
// not occupancy, is the lever -> accept VGPR ~140 / 3-4 waves per SIMD.
// No launch bounds (R9's cap forced spills and regressed).

constexpr int Wd = 4096;
constexpr int Ht = 4096;
constexpr int ROWS = 16;

typedef float f4 __attribute__((ext_vector_type(4)));
typedef float f2 __attribute__((ext_vector_type(2)));

__global__ __launch_bounds__(256) void canny_kernel(const float* __restrict__ x,
                                                    float* __restrict__ out) {
    const int tid  = threadIdx.x;
    const int lane = tid & 63;
    const int wv   = tid >> 6;
    const int wc   = blockIdx.x;                     // 256-col band, 0..15
    const int cbase = wc * 256;
    const int c     = cbase + lane * 4;              // lane's first col
    const int r0    = (blockIdx.y * 4 + wv) * ROWS;  // wave's first output row

    // ---- Main loads: 18 coalesced f4 row-chunks (1KB/instruction) ----
    f4 X[ROWS + 2];
    #pragma unroll
    for (int k = 0; k < ROWS + 2; ++k) {
        int rr = r0 - 1 + k;
        rr = rr < 0 ? 0 : (rr > Ht - 1 ? Ht - 1 : rr);  // border rows zeroed below
        X[k] = *(const f4*)(x + (size_t)rr * Wd + c);
    }

    // ---- Halo: ONE masked load covers both sides x all 18 window rows ----
    // lane k (k<18): left halo f2 (cols cbase-2,-1) of row r0-1+k
    // lane 32+k:     right halo f2 (cols cbase+256,+257) of row r0-1+k
    f2 hl = {0.f, 0.f};
    {
        const int  hk    = lane & 31;
        const bool left  = lane < 32;
        const bool valid = (hk < ROWS + 2) && (left ? (wc > 0) : (wc < 15));
        if (valid) {
            int rr = r0 - 1 + hk;
            rr = rr < 0 ? 0 : (rr > Ht - 1 ? Ht - 1 : rr);
            const int hc = left ? cbase - 2 : cbase + 256;
            hl = *(const f2*)(x + (size_t)rr * Wd + hc);
        }
    }
    // Per-lane halo t: lane (side*32 + o) holds the t-halo for output row r0+o.
    const float s1x = __shfl_down(hl.x, 1), s2x = __shfl_down(hl.x, 2);
    const float s1y = __shfl_down(hl.y, 1), s2y = __shfl_down(hl.y, 2);
    const float th1x = hl.x + 2.0f * s1x + s2x;   // t1 of halo col 0
    const float th1y = hl.y + 2.0f * s1y + s2y;   // t1 of halo col 1
    const float th2x = hl.x - s2x;                // t2 of halo col 0
    const float th2y = hl.y - s2y;                // t2 of halo col 1

    const float C1  = __uint_as_float(0x3CB851EDu);  // q > C1  <=> sqrt(q) > 0.15f
    const float C2B = __uint_as_float(0x3B23D709u);  // q > C2B <=> sqrt(q) >= 0.05f

    #pragma unroll
    for (int o = 0; o < ROWS; ++o) {
        const int r = r0 + o;
        f4 a = X[o], b = X[o + 1], cc = X[o + 2];

        // Vertical pass for own 4 cols: t1 = a+2b+c (gx), t2 = a-c (gy).
        float t1[4], t2[4];
        #pragma unroll
        for (int j = 0; j < 4; ++j) {
            t1[j] = a[j] + 2.0f * b[j] + cc[j];
            t2[j] = a[j] - cc[j];
        }

        // Halo broadcast: lane 0 wants left (lane o), lane 63 right (lane 32+o).
        const int hidx = (lane == 63) ? 32 + o : o;
        const float b1x = __shfl(th1x, hidx);
        const float b1y = __shfl(th1y, hidx);
        const float b2x = __shfl(th2x, hidx);
        const float b2y = __shfl(th2y, hidx);

        // Neighbor t via shuffle: left lane's cols 2,3 / right lane's cols 0,1.
        float l1a = __shfl_up(t1[2], 1),   l1b = __shfl_up(t1[3], 1);
        float l2a = __shfl_up(t2[2], 1),   l2b = __shfl_up(t2[3], 1);
        float r1a = __shfl_down(t1[0], 1), r1b = __shfl_down(t1[1], 1);
        float r2a = __shfl_down(t2[0], 1), r2b = __shfl_down(t2[1], 1);
        if (lane == 0)  { l1a = b1x; l1b = b1y; l2a = b2x; l2b = b2y; }
        if (lane == 63) { r1a = b1x; r1b = b1y; r2a = b2x; r2b = b2y; }

        // T index k = image col c + (k-2), k = 0..7.
        float T1[8] = {l1a, l1b, t1[0], t1[1], t1[2], t1[3], r1a, r1b};
        float T2[8] = {l2a, l2b, t2[0], t2[1], t2[2], t2[3], r2a, r2b};

        // Squared gradient magnitude q[i] at image col c + (i-1), i = 0..5.
        float q[6];
        #pragma unroll
        for (int i = 0; i < 6; ++i) {
            float gx = T1[i + 2] - T1[i];
            float gy = T2[i] + 2.0f * T2[i + 1] + T2[i + 2];
            q[i] = gx * gx + gy * gy;
        }

        // Hazard net: near-tie q pairs could flip >= after sqrt rounding.
        bool hazard = false;
        #pragma unroll
        for (int i = 0; i < 5; ++i) {
            int d = (int)(__float_as_uint(q[i + 1]) - __float_as_uint(q[i]));
            hazard |= ((unsigned)(d + 8) < 17u);
        }

        float acc[4];
        #pragma unroll
        for (int o2 = 0; o2 < 4; ++o2) {
            float qp = q[o2], qc = q[o2 + 1], qn = q[o2 + 2];
            bool keep = (qc >= qp) && (qc >= qn);
            acc[o2] = (keep && qc > C1) ? 255.0f : 0.0f;
            hazard |= (keep && qc > 0.0f && qc <= C2B);  // pass-through needs sqrt
        }

        if (__any(hazard)) {
            // Exact reference path (rare).
            float m[6];
            #pragma unroll
            for (int i = 0; i < 6; ++i) m[i] = sqrtf(q[i]);
            #pragma unroll
            for (int o2 = 0; o2 < 4; ++o2) {
                float mc = m[o2 + 1];
                bool keep = (mc >= m[o2]) && (mc >= m[o2 + 2]);
                float e = keep ? mc : 0.0f;
                acc[o2] = (e > 0.15f) ? 255.0f : ((e >= 0.05f) ? 0.0f : e);
            }
        }

        // Zero border shell, exactly as the reference.
        if (r == 0 || r == Ht - 1) {
            #pragma unroll
            for (int o2 = 0; o2 < 4; ++o2) acc[o2] = 0.0f;
        }
        if (wc == 0  && lane == 0)  acc[0] = 0.0f;
        if (wc == 15 && lane == 63) acc[3] = 0.0f;

        f4 v = {acc[0], acc[1], acc[2], acc[3]};
        __builtin_nontemporal_store(v, (f4*)(out + (size_t)r * Wd + c));
    }
}

extern "C" void kernel_launch(void* const* d_in, const int* in_sizes, int n_in,
                              void* d_out, int out_size, void* d_ws, size_t ws_size,
                              hipStream_t stream) {
    const float* x = (const float*)d_in[0];
    float* out = (float*)d_out;
    dim3 grid(16, 64);   // 16 col-bands x 64 blocks of (4 waves x 16 rows)
    canny_kernel<<<grid, dim3(256), 0, stream>>>(x, out);
}

// Round 12
// 110.929 us; speedup vs baseline: 1.0952x; 1.0212x over previous
//
#include <hip/hip_runtime.h>
#include <math.h>

// Canny-style Sobel NMS + double threshold on 4096x4096 f32.
// Reference's direction predicate b1 is vacuously true -> NMS is horizontal.
//
// R12: R8's byte structure (ROWS=8, 1.25x read amp, packed one-instruction
// halo, shfl horizontal sharing) with two latency fixes:
//  1. 64-thread blocks (= 1 wave). No __syncthreads anywhere, so 256-thread
//     blocks were pure scheduling coarseness: R11 showed 21% occupancy from
//     block-granular residency/retirement. Wave-sized blocks let the CU
//     refill continuously.
//  2. sched_barrier(0) after the load section: R11's VGPR=72 proved the
//     compiler software-pipelines fully-unrolled bodies, destroying the
//     up-front MLP. The barrier pins all 11 loads in flight before compute.
// Math identical to the verified absmax-0.0 path: exact squared-domain NMS +
// double threshold with integer hazard net -> rare sqrtf reference fallback.

constexpr int Wd = 4096;
constexpr int Ht = 4096;
constexpr int ROWS = 8;

typedef float f4 __attribute__((ext_vector_type(4)));
typedef float f2 __attribute__((ext_vector_type(2)));

__global__ __launch_bounds__(64) void canny_kernel(const float* __restrict__ x,
                                                   float* __restrict__ out) {
    const int lane = threadIdx.x;                    // block == wave
    const int wc   = blockIdx.x;                     // 256-col band, 0..15
    const int cbase = wc * 256;
    const int c     = cbase + lane * 4;              // lane's first col
    const int r0    = blockIdx.y * ROWS;             // wave's first output row

    // ---- Main loads: 10 coalesced f4 row-chunks (1KB/instruction) ----
    f4 X[ROWS + 2];
    #pragma unroll
    for (int k = 0; k < ROWS + 2; ++k) {
        int rr = r0 - 1 + k;
        rr = rr < 0 ? 0 : (rr > Ht - 1 ? Ht - 1 : rr);  // border rows zeroed below
        X[k] = *(const f4*)(x + (size_t)rr * Wd + c);
    }

    // ---- Halo: ONE masked load covers both sides x all 10 window rows ----
    // lane k (k<10): left halo f2 (cols cbase-2,-1) of row r0-1+k
    // lane 32+k:     right halo f2 (cols cbase+256,+257) of row r0-1+k
    f2 hl = {0.f, 0.f};
    {
        const int  hk    = lane & 31;
        const bool left  = lane < 32;
        const bool valid = (hk < ROWS + 2) && (left ? (wc > 0) : (wc < 15));
        if (valid) {
            int rr = r0 - 1 + hk;
            rr = rr < 0 ? 0 : (rr > Ht - 1 ? Ht - 1 : rr);
            const int hc = left ? cbase - 2 : cbase + 256;
            hl = *(const f2*)(x + (size_t)rr * Wd + hc);
        }
    }

    // Pin all loads above this point: prevent the compiler from software-
    // pipelining them down to their consumers (R11 failure mode).
    __builtin_amdgcn_sched_barrier(0);

    // Per-lane halo t: lane (side*32 + o) holds the t-halo for output row r0+o.
    const float s1x = __shfl_down(hl.x, 1), s2x = __shfl_down(hl.x, 2);
    const float s1y = __shfl_down(hl.y, 1), s2y = __shfl_down(hl.y, 2);
    const float th1x = hl.x + 2.0f * s1x + s2x;   // t1 of halo col 0
    const float th1y = hl.y + 2.0f * s1y + s2y;   // t1 of halo col 1
    const float th2x = hl.x - s2x;                // t2 of halo col 0
    const float th2y = hl.y - s2y;                // t2 of halo col 1

    const float C1  = __uint_as_float(0x3CB851EDu);  // q > C1  <=> sqrt(q) > 0.15f
    const float C2B = __uint_as_float(0x3B23D709u);  // q > C2B <=> sqrt(q) >= 0.05f

    #pragma unroll
    for (int o = 0; o < ROWS; ++o) {
        const int r = r0 + o;
        f4 a = X[o], b = X[o + 1], cc = X[o + 2];

        // Vertical pass for own 4 cols: t1 = a+2b+c (gx), t2 = a-c (gy).
        float t1[4], t2[4];
        #pragma unroll
        for (int j = 0; j < 4; ++j) {
            t1[j] = a[j] + 2.0f * b[j] + cc[j];
            t2[j] = a[j] - cc[j];
        }

        // Halo broadcast: lane 0 wants left (lane o), lane 63 right (lane 32+o).
        const int hidx = (lane == 63) ? 32 + o : o;
        const float b1x = __shfl(th1x, hidx);
        const float b1y = __shfl(th1y, hidx);
        const float b2x = __shfl(th2x, hidx);
        const float b2y = __shfl(th2y, hidx);

        // Neighbor t via shuffle: left lane's cols 2,3 / right lane's cols 0,1.
        float l1a = __shfl_up(t1[2], 1),   l1b = __shfl_up(t1[3], 1);
        float l2a = __shfl_up(t2[2], 1),   l2b = __shfl_up(t2[3], 1);
        float r1a = __shfl_down(t1[0], 1), r1b = __shfl_down(t1[1], 1);
        float r2a = __shfl_down(t2[0], 1), r2b = __shfl_down(t2[1], 1);
        if (lane == 0)  { l1a = b1x; l1b = b1y; l2a = b2x; l2b = b2y; }
        if (lane == 63) { r1a = b1x; r1b = b1y; r2a = b2x; r2b = b2y; }

        // T index k = image col c + (k-2), k = 0..7.
        float T1[8] = {l1a, l1b, t1[0], t1[1], t1[2], t1[3], r1a, r1b};
        float T2[8] = {l2a, l2b, t2[0], t2[1], t2[2], t2[3], r2a, r2b};

        // Squared gradient magnitude q[i] at image col c + (i-1), i = 0..5.
        float q[6];
        #pragma unroll
        for (int i = 0; i < 6; ++i) {
            float gx = T1[i + 2] - T1[i];
            float gy = T2[i] + 2.0f * T2[i + 1] + T2[i + 2];
            q[i] = gx * gx + gy * gy;
        }

        // Hazard net: near-tie q pairs could flip >= after sqrt rounding.
        bool hazard = false;
        #pragma unroll
        for (int i = 0; i < 5; ++i) {
            int d = (int)(__float_as_uint(q[i + 1]) - __float_as_uint(q[i]));
            hazard |= ((unsigned)(d + 8) < 17u);
        }

        float acc[4];
        #pragma unroll
        for (int o2 = 0; o2 < 4; ++o2) {
            float qp = q[o2], qc = q[o2 + 1], qn = q[o2 + 2];
            bool keep = (qc >= qp) && (qc >= qn);
            acc[o2] = (keep && qc > C1) ? 255.0f : 0.0f;
            hazard |= (keep && qc > 0.0f && qc <= C2B);  // pass-through needs sqrt
        }

        if (__any(hazard)) {
            // Exact reference path (rare).
            float m[6];
            #pragma unroll
            for (int i = 0; i < 6; ++i) m[i] = sqrtf(q[i]);
            #pragma unroll
            for (int o2 = 0; o2 < 4; ++o2) {
                float mc = m[o2 + 1];
                bool keep = (mc >= m[o2]) && (mc >= m[o2 + 2]);
                float e = keep ? mc : 0.0f;
                acc[o2] = (e > 0.15f) ? 255.0f : ((e >= 0.05f) ? 0.0f : e);
            }
        }

        // Zero border shell, exactly as the reference.
        if (r == 0 || r == Ht - 1) {
            #pragma unroll
            for (int o2 = 0; o2 < 4; ++o2) acc[o2] = 0.0f;
        }
        if (wc == 0  && lane == 0)  acc[0] = 0.0f;
        if (wc == 15 && lane == 63) acc[3] = 0.0f;

        f4 v = {acc[0], acc[1], acc[2], acc[3]};
        __builtin_nontemporal_store(v, (f4*)(out + (size_t)r * Wd + c));
    }
}

extern "C" void kernel_launch(void* const* d_in, const int* in_sizes, int n_in,
                              void* d_out, int out_size, void* d_ws, size_t ws_size,
                              hipStream_t stream) {
    const float* x = (const float*)d_in[0];
    float* out = (float*)d_out;
    dim3 grid(16, 512);   // 16 col-bands x 512 wave-blocks of 8 rows
    canny_kernel<<<grid, dim3(64), 0, stream>>>(x, out);
}